// Round 2
// baseline (332.953 us; speedup 1.0000x reference)
//
#include <hip/hip_runtime.h>
#include <stdint.h>

#define B_SZ   32768
#define F_SZ   512
#define G_SZ   16
#define L_SZ   64
#define N_COLS 1024   // G*L
#define C_SZ   1000
#define M_TILE 32
#define TILES_PER_BLK 2   // persistent: grid 512, each block pipelines 2 tiles
#define A_STRIDE 520      // ushorts per LDS A row (512+8; breaks pow2 stride)
// LDS union: A-stage 32*520*2 = 33280 B  vs  WT transposed 1024*16*4 = 65536 B
#define SMEM_BYTES 65536

typedef __attribute__((ext_vector_type(8))) short short8;
typedef __attribute__((ext_vector_type(4))) float floatx4;

__device__ __forceinline__ unsigned short f2bf(float f) {
    unsigned int x = __float_as_uint(f);
    x += 0x7fffu + ((x >> 16) & 1u);   // RNE to bf16
    return (unsigned short)(x >> 16);
}

// Raw workgroup barrier WITHOUT the vmcnt(0) drain __syncthreads() implies.
// Semantics we need at every sync point in this kernel are LDS-only:
//   - our ds_writes must be visible to other threads  -> lgkmcnt(0) before barrier
//   - global OUT-stores are never read back            -> no vmcnt wait needed
//   - prefetch global loads are guarded by their reg use (compiler waits)
// sched_barrier(0) pins code motion across the asm (guide rule #18).
__device__ __forceinline__ void barrier_lgkm() {
    __builtin_amdgcn_sched_barrier(0);
    asm volatile("s_waitcnt lgkmcnt(0)" ::: "memory");
    __builtin_amdgcn_s_barrier();
    __builtin_amdgcn_sched_barrier(0);
}

// ---- kernel 1: invert label_ids into CSR with a parallel scan; emit the column
//      permutation (list), permuted bias, and per-slot group id ----
__global__ __launch_bounds__(1024) void build_csr_kernel(const int* __restrict__ label_ids,
                                                         const float* __restrict__ bias,
                                                         int* __restrict__ off,
                                                         int* __restrict__ list,
                                                         float* __restrict__ bias_p,
                                                         unsigned char* __restrict__ g_perm) {
    __shared__ int cnt[1024];   // counts -> inclusive scan (classes padded to 1024)
    __shared__ int cur[1024];   // scatter cursors
    const int t = threadIdx.x;            // 0..1023 == column index g*64+l
    cnt[t] = 0;
    __syncthreads();
    const int lbl = label_ids[t];
    atomicAdd(&cnt[lbl], 1);
    __syncthreads();
    // Hillis-Steele inclusive scan over 1024 entries
    int v = cnt[t];
    #pragma unroll
    for (int d = 1; d < 1024; d <<= 1) {
        int u = (t >= d) ? cnt[t - d] : 0;
        __syncthreads();
        v += u;
        cnt[t] = v;
        __syncthreads();
    }
    // exclusive offset for this thread's class slot
    int ex = (t == 0) ? 0 : cnt[t - 1];
    cur[t] = ex;
    if (t <= C_SZ) off[t] = (t == 0) ? 0 : cnt[t - 1];   // off[1000] == 1024
    __syncthreads();
    int pos = atomicAdd(&cur[lbl], 1);
    list[pos]   = t;
    bias_p[pos] = bias[t];
    g_perm[pos] = (unsigned char)(t >> 6);
}

// ---- kernel 2: W f32 -> bf16, rows permuted into CSR-list order ----
__global__ __launch_bounds__(256) void convert_w_kernel(const float* __restrict__ W,
                                                        const int* __restrict__ list,
                                                        unsigned short* __restrict__ Wb) {
    int idx = blockIdx.x * 256 + threadIdx.x;        // float4 index, 131072 total
    int row = idx >> 7;                              // output row j
    int c4  = idx & 127;
    int src = list[row];                             // original column
    const float4* W4 = (const float4*)W;
    float4 v = W4[src * 128 + c4];
    ushort4 u = make_ushort4(f2bf(v.x), f2bf(v.y), f2bf(v.z), f2bf(v.w));
    ((ushort4*)Wb)[idx] = u;
}

// ---- kernel 3: persistent fused GEMM + weighting + contiguous-run gather ----
// Grid 512 blocks x 1024 threads, 2 blocks/CU, 2 row-tiles per block, pipelined:
//  - tile i+1's feat loads issue right after tile i's K-loop (HBM latency hides
//    under the epilogue; prefetch regs don't inflate K-loop pressure)
//  - ALL barriers are raw s_barrier + lgkmcnt(0) only: out-stores and prefetch
//    loads stay in flight across them (the __syncthreads vmcnt(0) drain was the
//    measured 100+ us of stall: all pipes <14% busy at 84% occupancy)
__global__ __launch_bounds__(1024, 8) void mhc_main_kernel(
        const float* __restrict__ feat,            // [B][512] f32
        const float* __restrict__ gp,              // [B][16]  f32
        const unsigned short* __restrict__ Wb,     // [1024][512] bf16, permuted rows
        const float* __restrict__ bias_p,          // [1024] f32, permuted
        const int* __restrict__ off,               // [1001]
        const unsigned char* __restrict__ g_perm,  // [1024] group of each permuted col
        float* __restrict__ out)                   // [B][1000] f32
{
    __shared__ __align__(16) char smem[SMEM_BYTES]; // A-stage aliased with WT tile
    __shared__ float gp_s[M_TILE * G_SZ];           // 32 rows x 16 groups
    __shared__ float bias_s[N_COLS];
    __shared__ unsigned char g_s[N_COLS];

    unsigned short* As = (unsigned short*)smem;
    float* WT = (float*)smem;   // transposed weighted tile: WT[col][16 rows], swizzled

    const int t    = threadIdx.x;
    const int wave = t >> 6;          // 0..15
    const int lane = t & 63;
    const int m16  = lane & 15;
    const int quad = lane >> 4;       // 0..3

    // tile-invariant staging
    bias_s[t] = bias_p[t];
    g_s[t]    = g_perm[t];
    int e0 = 0, e1 = 0;
    if (t < C_SZ) { e0 = off[t]; e1 = off[t + 1]; }

    // prefetch tile 0 (raw f32 in regs; converted at loop top)
    const floatx4* f4 = (const floatx4*)feat;
    floatx4 pf0, pf1, pf2, pf3;
    float pgp = 0.f;
    {
        size_t base = (size_t)blockIdx.x * TILES_PER_BLK * M_TILE * (F_SZ / 4);
        pf0 = __builtin_nontemporal_load(f4 + base + t);
        pf1 = __builtin_nontemporal_load(f4 + base + t + 1024);
        pf2 = __builtin_nontemporal_load(f4 + base + t + 2048);
        pf3 = __builtin_nontemporal_load(f4 + base + t + 3072);
        if (t < M_TILE * G_SZ)
            pgp = gp[(size_t)blockIdx.x * TILES_PER_BLK * M_TILE * G_SZ + t];
    }

    #pragma unroll
    for (int it = 0; it < TILES_PER_BLK; ++it) {
        const int tile = blockIdx.x * TILES_PER_BLK + it;
        const int r0   = tile * M_TILE;

        // guards: prev-tile gather reads of WT consumed; prologue ds-writes drained
        barrier_lgkm();

        // convert prefetched A -> bf16 LDS (loads arrived long ago except it=0)
        {
            floatx4 pr[4] = {pf0, pf1, pf2, pf3};
            #pragma unroll
            for (int i = 0; i < 4; ++i) {
                int idx = t + i * 1024;            // row = idx/128, c4 = idx%128
                int row = idx >> 7;
                int c4  = idx & 127;
                ushort4 u = make_ushort4(f2bf(pr[i][0]), f2bf(pr[i][1]),
                                         f2bf(pr[i][2]), f2bf(pr[i][3]));
                *(ushort4*)(As + row * A_STRIDE + c4 * 4) = u;
            }
            if (t < M_TILE * G_SZ) gp_s[t] = pgp;
        }
        barrier_lgkm();   // A + gp visible

        const floatx4 zero = {0.f, 0.f, 0.f, 0.f};
        floatx4 acc[2][4];
        #pragma unroll
        for (int i = 0; i < 2; ++i)
            #pragma unroll
            for (int j = 0; j < 4; ++j) acc[i][j] = zero;

        const unsigned short* aBase = As + m16 * A_STRIDE + quad * 8;
        const unsigned short* bBase = Wb + (size_t)(wave * 64 + m16) * F_SZ + quad * 8;

        #pragma unroll 2
        for (int kt = 0; kt < 16; ++kt) {             // K step = 32
            short8 a0 = *(const short8*)(aBase + kt * 32);
            short8 a1 = *(const short8*)(aBase + 16 * A_STRIDE + kt * 32);
            #pragma unroll
            for (int ct = 0; ct < 4; ++ct) {
                short8 b = *(const short8*)(bBase + ct * 16 * F_SZ + kt * 32);
                acc[0][ct] = __builtin_amdgcn_mfma_f32_16x16x32_bf16(a0, b, acc[0][ct], 0, 0, 0);
                acc[1][ct] = __builtin_amdgcn_mfma_f32_16x16x32_bf16(a1, b, acc[1][ct], 0, 0, 0);
            }
        }

        // prefetch next tile HERE: latency hides under the epilogue, and the
        // 16 in-flight regs don't coexist with peak K-loop pressure
        if (it + 1 < TILES_PER_BLK) {
            size_t base = (size_t)(tile + 1) * M_TILE * (F_SZ / 4);
            pf0 = __builtin_nontemporal_load(f4 + base + t);
            pf1 = __builtin_nontemporal_load(f4 + base + t + 1024);
            pf2 = __builtin_nontemporal_load(f4 + base + t + 2048);
            pf3 = __builtin_nontemporal_load(f4 + base + t + 3072);
            if (t < M_TILE * G_SZ)
                pgp = gp[(size_t)(tile + 1) * M_TILE * G_SZ + t];
        }

        // epilogue: 2 passes of 16 rows, TRANSPOSED layout WT[col][16 rows].
        #pragma unroll
        for (int p = 0; p < 2; ++p) {
            barrier_lgkm();   // p0: K-loop A-LDS reads done; p1: pass-0 gather done
            #pragma unroll
            for (int ct = 0; ct < 4; ++ct) {
                int col = wave * 64 + ct * 16 + m16;
                int g   = g_s[col];
                float bi = bias_s[col];
                int slot = quad ^ ((col ^ (col >> 2)) & 3);
                floatx4 w;
                #pragma unroll
                for (int r = 0; r < 4; ++r) {
                    int rl = quad * 4 + r;                       // local row 0..15 (C/D layout)
                    w[r] = gp_s[(p * 16 + rl) * G_SZ + g] * (acc[p][ct][r] + bi);
                }
                *(floatx4*)(WT + col * 16 + slot * 4) = w;
            }
            barrier_lgkm();   // WT visible to gatherers
            if (t < C_SZ) {
                float s[16];
                #pragma unroll
                for (int i = 0; i < 16; ++i) s[i] = 0.f;
                for (int j = e0; j < e1; ++j) {
                    int sw = (j ^ (j >> 2)) & 3;
                    const float* cbase = WT + j * 16;
                    #pragma unroll
                    for (int q = 0; q < 4; ++q) {
                        floatx4 v = *(const floatx4*)(cbase + ((q ^ sw) << 2));
                        s[q * 4 + 0] += v[0];
                        s[q * 4 + 1] += v[1];
                        s[q * 4 + 2] += v[2];
                        s[q * 4 + 3] += v[3];
                    }
                }
                size_t rowg = (size_t)(r0 + p * 16);
                #pragma unroll
                for (int rr = 0; rr < 16; ++rr)
                    out[(rowg + rr) * C_SZ + t] = s[rr];   // plain stores: fire-and-forget,
                                                           // never drained by our barriers
            }
        }
    }
}

extern "C" void kernel_launch(void* const* d_in, const int* in_sizes, int n_in,
                              void* d_out, int out_size, void* d_ws, size_t ws_size,
                              hipStream_t stream) {
    const float* feat  = (const float*)d_in[0];
    const float* gp    = (const float*)d_in[1];
    const float* W     = (const float*)d_in[2];
    const float* bias  = (const float*)d_in[3];
    const int* labels  = (const int*)d_in[4];
    float* out = (float*)d_out;

    unsigned short* Wb = (unsigned short*)d_ws;                    // 1 MiB bf16 W (permuted)
    char* base = (char*)d_ws + (1 << 20);
    int* off             = (int*)base;                             // 1001 ints (pad 4 KB)
    int* list            = (int*)(base + 4096);                    // 1024 ints
    float* bias_p        = (float*)(base + 8192);                  // 1024 f32
    unsigned char* g_prm = (unsigned char*)(base + 12288);         // 1024 bytes

    build_csr_kernel<<<1, 1024, 0, stream>>>(labels, bias, off, list, bias_p, g_prm);
    convert_w_kernel<<<(N_COLS * F_SZ / 4) / 256, 256, 0, stream>>>(W, list, Wb);
    mhc_main_kernel<<<B_SZ / (M_TILE * TILES_PER_BLK), 1024, 0, stream>>>(feat, gp, Wb, bias_p, off, g_prm, out);
}

// Round 3
// 257.966 us; speedup vs baseline: 1.2907x; 1.2907x over previous
//
#include <hip/hip_runtime.h>
#include <stdint.h>

#define B_SZ   32768
#define F_SZ   512
#define G_SZ   16
#define L_SZ   64
#define N_COLS 1024   // G*L
#define C_SZ   1000
#define M_TILE 64
#define A_STRIDE 520    // ushorts per LDS A row (512+8; keeps 16B alignment, breaks pow2 stride)
#define W_STRIDE 1042   // floats per LDS weighted row (1042 % 8 == 2 -> quads spread over banks 0/8/16/24)
#define SMEM_BYTES 66688  // max(64*520*2 = 66560, 16*1042*4 = 66688)

typedef __attribute__((ext_vector_type(8))) short short8;
typedef __attribute__((ext_vector_type(4))) float floatx4;

__device__ __forceinline__ unsigned short f2bf(float f) {
    unsigned int x = __float_as_uint(f);
    x += 0x7fffu + ((x >> 16) & 1u);   // RNE to bf16
    return (unsigned short)(x >> 16);
}

// Raw workgroup barrier WITHOUT the vmcnt(0) drain __syncthreads() implies.
// Every sync point in mhc_main is an LDS-only hazard:
//   - ds_writes must be visible to other threads       -> lgkmcnt(0) before barrier
//   - prior-pass LDS *reads* must have completed       -> also lgkmcnt
//   - global OUT-stores are never read back            -> no vmcnt wait needed
//   - global loads are consumed via registers          -> compiler inserts vmcnt at use
// This keeps out-stores and A-stage fetches in flight across barriers; measured
// r0 spent ~75% of kernel time stalled with 1 block/CU and nothing to overlap.
// sched_barrier(0) pins code motion across the asm (guide rule #18).
__device__ __forceinline__ void barrier_lgkm() {
    __builtin_amdgcn_sched_barrier(0);
    asm volatile("s_waitcnt lgkmcnt(0)" ::: "memory");
    __builtin_amdgcn_s_barrier();
    __builtin_amdgcn_sched_barrier(0);
}

// ---- kernel 1: invert label_ids into CSR with a parallel scan; emit the column
//      permutation (list), permuted bias, and per-slot group id ----
__global__ __launch_bounds__(1024) void build_csr_kernel(const int* __restrict__ label_ids,
                                                         const float* __restrict__ bias,
                                                         int* __restrict__ off,
                                                         int* __restrict__ list,
                                                         float* __restrict__ bias_p,
                                                         unsigned char* __restrict__ g_perm) {
    __shared__ int cnt[1024];   // counts -> inclusive scan (classes padded to 1024)
    __shared__ int cur[1024];   // scatter cursors
    const int t = threadIdx.x;            // 0..1023 == column index g*64+l
    cnt[t] = 0;
    __syncthreads();
    const int lbl = label_ids[t];
    atomicAdd(&cnt[lbl], 1);
    __syncthreads();
    // Hillis-Steele inclusive scan over 1024 entries
    int v = cnt[t];
    #pragma unroll
    for (int d = 1; d < 1024; d <<= 1) {
        int u = (t >= d) ? cnt[t - d] : 0;
        __syncthreads();
        v += u;
        cnt[t] = v;
        __syncthreads();
    }
    // exclusive offset for this thread's class slot
    int ex = (t == 0) ? 0 : cnt[t - 1];
    cur[t] = ex;
    if (t <= C_SZ) off[t] = (t == 0) ? 0 : cnt[t - 1];   // off[1000] == 1024
    __syncthreads();
    int pos = atomicAdd(&cur[lbl], 1);
    list[pos]   = t;
    bias_p[pos] = bias[t];
    g_perm[pos] = (unsigned char)(t >> 6);
}

// ---- kernel 2: W f32 -> bf16, rows permuted into CSR-list order ----
__global__ __launch_bounds__(256) void convert_w_kernel(const float* __restrict__ W,
                                                        const int* __restrict__ list,
                                                        unsigned short* __restrict__ Wb) {
    int idx = blockIdx.x * 256 + threadIdx.x;        // float4 index, 131072 total
    int row = idx >> 7;                              // output row j
    int c4  = idx & 127;
    int src = list[row];                             // original column
    const float4* W4 = (const float4*)W;
    float4 v = W4[src * 128 + c4];
    ushort4 u = make_ushort4(f2bf(v.x), f2bf(v.y), f2bf(v.z), f2bf(v.w));
    ((ushort4*)Wb)[idx] = u;
}

// ---- kernel 3: fused GEMM (bf16 MFMA) + weighting + contiguous-run gather ----
// Block: 1024 threads = 16 waves. Tile: 64 rows x ALL 1024 (permuted) cols. K=512.
// EXACT r0 structure (measured 133 us, 1 block/CU, no spills); single change:
// all __syncthreads() -> barrier_lgkm() so the 4x-per-block out-store bursts and
// the A-stage fetch are never vmcnt(0)-drained at barriers.
__global__ __launch_bounds__(1024, 4) void mhc_main_kernel(
        const float* __restrict__ feat,            // [B][512] f32
        const float* __restrict__ gp,              // [B][16]  f32
        const unsigned short* __restrict__ Wb,     // [1024][512] bf16, permuted rows
        const float* __restrict__ bias_p,          // [1024] f32, permuted
        const int* __restrict__ off,               // [1001]
        const unsigned char* __restrict__ g_perm,  // [1024] group of each permuted col
        float* __restrict__ out)                   // [B][1000] f32
{
    __shared__ __align__(16) char smem[SMEM_BYTES]; // A-stage aliased with weighted tile
    __shared__ float gp_s[M_TILE * G_SZ];           // 64 rows x 16 groups
    __shared__ float bias_s[N_COLS];
    __shared__ unsigned char g_s[N_COLS];

    unsigned short* As = (unsigned short*)smem;
    float* WL = (float*)smem;

    const int t    = threadIdx.x;
    const int wave = t >> 6;          // 0..15
    const int lane = t & 63;
    const int m16  = lane & 15;
    const int quad = lane >> 4;       // 0..3
    const int r0   = blockIdx.x * M_TILE;

    // stage group_probs tile + permuted bias + per-col group
    gp_s[t]   = gp[r0 * G_SZ + t];
    bias_s[t] = bias_p[t];
    g_s[t]    = g_perm[t];

    // this thread's contiguous gather run (pass-invariant, lives in registers)
    int e0 = 0, e1 = 0;
    if (t < C_SZ) { e0 = off[t]; e1 = off[t + 1]; }

    // stage A: 64 rows x 512 f32 -> bf16 LDS, coalesced float4 reads
    {
        const float4* f4 = (const float4*)(feat + (size_t)r0 * F_SZ);
        #pragma unroll
        for (int i = 0; i < 8; ++i) {
            int idx = t + i * 1024;            // row = idx/128, c4 = idx%128
            int row = idx >> 7;
            int c4  = idx & 127;
            float4 v = f4[idx];
            ushort4 u = make_ushort4(f2bf(v.x), f2bf(v.y), f2bf(v.z), f2bf(v.w));
            *(ushort4*)(As + row * A_STRIDE + c4 * 4) = u;
        }
    }
    barrier_lgkm();   // A + gp/bias/g_s visible (all LDS writes covered by lgkmcnt)

    const floatx4 zero = {0.f, 0.f, 0.f, 0.f};
    floatx4 acc[4][4];
    #pragma unroll
    for (int i = 0; i < 4; ++i)
        #pragma unroll
        for (int j = 0; j < 4; ++j) acc[i][j] = zero;

    const unsigned short* aBase = As + m16 * A_STRIDE + quad * 8;
    const unsigned short* bBase = Wb + (size_t)(wave * 64 + m16) * F_SZ + quad * 8;

    #pragma unroll 4
    for (int kt = 0; kt < 16; ++kt) {             // K step = 32
        short8 a[4];
        #pragma unroll
        for (int rt = 0; rt < 4; ++rt)
            a[rt] = *(const short8*)(aBase + rt * 16 * A_STRIDE + kt * 32);
        #pragma unroll
        for (int ct = 0; ct < 4; ++ct) {
            short8 b = *(const short8*)(bBase + ct * 16 * F_SZ + kt * 32);
            #pragma unroll
            for (int rt = 0; rt < 4; ++rt)
                acc[rt][ct] = __builtin_amdgcn_mfma_f32_16x16x32_bf16(a[rt], b, acc[rt][ct], 0, 0, 0);
        }
    }

    // epilogue: 4 passes of 16 rows. weighted -> LDS, then contiguous-run gather -> out.
    // FULLY UNROLLED so acc[p][...] indexing is static (dynamic p spilled — round 2 of
    // the previous session). Out-stores are fire-and-forget: no barrier drains them.
    #pragma unroll
    for (int p = 0; p < 4; ++p) {
        barrier_lgkm();   // pass 0: guards A-LDS K-loop reads; later: guards prior gather reads
        #pragma unroll
        for (int ct = 0; ct < 4; ++ct) {
            int col = wave * 64 + ct * 16 + m16;
            int g   = g_s[col];
            float bi = bias_s[col];
            #pragma unroll
            for (int r = 0; r < 4; ++r) {
                int rl = quad * 4 + r;                           // local row 0..15 (C/D layout)
                float v = gp_s[(p * 16 + rl) * G_SZ + g] * (acc[p][ct][r] + bi);
                WL[rl * W_STRIDE + col] = v;
            }
        }
        barrier_lgkm();   // WL visible to gatherers
        if (t < C_SZ) {
            #pragma unroll
            for (int h = 0; h < 4; ++h) {                        // 4 rows per chunk
                float s0 = 0.f, s1 = 0.f, s2 = 0.f, s3 = 0.f;
                for (int j = e0; j < e1; ++j) {
                    s0 += WL[(h * 4 + 0) * W_STRIDE + j];
                    s1 += WL[(h * 4 + 1) * W_STRIDE + j];
                    s2 += WL[(h * 4 + 2) * W_STRIDE + j];
                    s3 += WL[(h * 4 + 3) * W_STRIDE + j];
                }
                size_t rowg = (size_t)(r0 + p * 16 + h * 4);
                out[(rowg + 0) * C_SZ + t] = s0;
                out[(rowg + 1) * C_SZ + t] = s1;
                out[(rowg + 2) * C_SZ + t] = s2;
                out[(rowg + 3) * C_SZ + t] = s3;
            }
        }
    }
}

extern "C" void kernel_launch(void* const* d_in, const int* in_sizes, int n_in,
                              void* d_out, int out_size, void* d_ws, size_t ws_size,
                              hipStream_t stream) {
    const float* feat  = (const float*)d_in[0];
    const float* gp    = (const float*)d_in[1];
    const float* W     = (const float*)d_in[2];
    const float* bias  = (const float*)d_in[3];
    const int* labels  = (const int*)d_in[4];
    float* out = (float*)d_out;

    unsigned short* Wb = (unsigned short*)d_ws;                    // 1 MiB bf16 W (permuted)
    char* base = (char*)d_ws + (1 << 20);
    int* off             = (int*)base;                             // 1001 ints (pad 4 KB)
    int* list            = (int*)(base + 4096);                    // 1024 ints
    float* bias_p        = (float*)(base + 8192);                  // 1024 f32
    unsigned char* g_prm = (unsigned char*)(base + 12288);         // 1024 bytes

    build_csr_kernel<<<1, 1024, 0, stream>>>(labels, bias, off, list, bias_p, g_prm);
    convert_w_kernel<<<(N_COLS * F_SZ / 4) / 256, 256, 0, stream>>>(W, list, Wb);
    mhc_main_kernel<<<B_SZ / M_TILE, 1024, 0, stream>>>(feat, gp, Wb, bias_p, off, g_prm, out);
}